// Round 2
// baseline (256.482 us; speedup 1.0000x reference)
//
#include <hip/hip_runtime.h>

#define NUM_NODES   120000
#define NUM_MOVABLE 100000
#define NUM_NETS    100000
#define NUM_PINS    400000
#define NBX 256
#define NBY 256
#define GRID (NBX*NBY)

constexpr float BSX      = 1000.0f / 256.0f;   // 3.90625 exact in binary
constexpr float INV_BS   = 256.0f / 1000.0f;
constexpr float BIN_AREA = BSX * BSX;
constexpr float EPSV     = 1e-6f;

// Workspace layout (all offsets in elements):
//   bmin:  u32[2*NUM_NETS]   (xmn, ymn encodings; memset 0xFF)
//   bmax:  u32[2*NUM_NETS]   (xmx, ymx encodings; memset 0x00)
//   W8:    float[GRID*8]     interleaved fields per bin (memset 0):
//            f0 P_h, f1 Cx_h(y-scan), f2 Cy_h(x-scan), f3 Q_h(y+x scan)
//            f4..f7 same for V
//   util:  float[GRID]       util[x*NBY+y]

// ---------------------------------------------------------------- pin phase
// One thread per pin slot. net_id is non-decreasing in slot order, so do a
// wave-segmented min/max scan and let only segment tails issue atomics.
__global__ void pin_bbox(const float* __restrict__ pin_pos,
                         const int* __restrict__ netpin_start,
                         const int* __restrict__ flat_netpin,
                         unsigned* __restrict__ bmin,
                         unsigned* __restrict__ bmax) {
    int t = blockIdx.x * 256 + threadIdx.x;
    int net = -1;
    float xmn = 3.4e38f, xmx = -3.4e38f, ymn = 3.4e38f, ymx = -3.4e38f;
    if (t < NUM_PINS) {
        // upper_bound over netpin_start (NUM_NETS+1 entries), minus 1
        int lo = 0, hi = NUM_NETS + 1;
        while (lo < hi) {
            int mid = (lo + hi) >> 1;
            if (netpin_start[mid] <= t) lo = mid + 1; else hi = mid;
        }
        net = min(lo - 1, NUM_NETS - 1);
        int p = flat_netpin[t];
        float px = pin_pos[p];
        float py = pin_pos[NUM_PINS + p];
        xmn = px; xmx = px; ymn = py; ymx = py;
    }
    int lane = threadIdx.x & 63;
    // segmented inclusive scan (min/max) over the 64-lane wave
    for (int d = 1; d < 64; d <<= 1) {
        int   on = __shfl_up(net, d);
        float a  = __shfl_up(xmn, d);
        float b  = __shfl_up(xmx, d);
        float c  = __shfl_up(ymn, d);
        float e  = __shfl_up(ymx, d);
        if (lane >= d && on == net) {
            xmn = fminf(xmn, a); xmx = fmaxf(xmx, b);
            ymn = fminf(ymn, c); ymx = fmaxf(ymx, e);
        }
    }
    int nextnet = __shfl_down(net, 1);
    bool tail = (lane == 63) || (nextnet != net);
    if (tail && net >= 0) {
        // coords are >= 0 so float bit patterns are order-preserving as u32
        atomicMin(bmin + net,            __float_as_uint(xmn));
        atomicMin(bmin + NUM_NETS + net, __float_as_uint(ymn));
        atomicMax(bmax + net,            __float_as_uint(xmx));
        atomicMax(bmax + NUM_NETS + net, __float_as_uint(ymx));
    }
}

// ---------------------------------------------------------------- splat phase
// One thread per (net, corner). Each corner's 8 field-adds are contiguous
// (32B) -> one cache line per corner instead of 8 scattered lines.
__global__ void net_splat2(const unsigned* __restrict__ bmin,
                           const unsigned* __restrict__ bmax,
                           float* __restrict__ W) {
    int t = blockIdx.x * 256 + threadIdx.x;
    if (t >= 4 * NUM_NETS) return;
    int n = t >> 2;
    int c = t & 3;           // 0:(lo,lo,+) 1:(lo,hi,-) 2:(hi,lo,-) 3:(hi,hi,+)

    unsigned emnx = bmin[n];
    if (emnx == 0xFFFFFFFFu) return;   // empty net
    float xmn = __uint_as_float(emnx);
    float ymn = __uint_as_float(bmin[NUM_NETS + n]);
    float xmx = __uint_as_float(bmax[n]);
    float ymx = __uint_as_float(bmax[NUM_NETS + n]);

    float span_x = xmx - xmn, span_y = ymx - ymn;
    float coef_h = (span_y > EPSV) ? 1.0f / span_y : 0.0f;
    float coef_v = (span_x > EPSV) ? 1.0f / span_x : 0.0f;
    if (coef_h == 0.0f && coef_v == 0.0f) return;

    int bxl = min((int)(xmn * INV_BS), NBX - 1);
    int bxh = min((int)(xmx * INV_BS), NBX - 1);
    int byl = min((int)(ymn * INV_BS), NBY - 1);
    int byh = min((int)(ymx * INV_BS), NBY - 1);

    int   bx  = (c & 2) ? bxh : bxl;
    int   by  = (c & 1) ? byh : byl;
    float rx  = (c & 2) ? ((float)(bxh + 1) * BSX - xmx) : ((float)(bxl + 1) * BSX - xmn);
    float ry  = (c & 1) ? ((float)(byh + 1) * BSX - ymx) : ((float)(byl + 1) * BSX - ymn);
    float sgn = ((c == 0) | (c == 3)) ? 1.0f : -1.0f;

    float* base = W + (size_t)(bx * NBY + by) * 8;
    if (coef_h != 0.0f) {
        float w = sgn * coef_h;
        atomicAdd(base + 0, w * rx  * ry);
        atomicAdd(base + 1, w * rx  * BSX);
        atomicAdd(base + 2, w * BSX * ry);
        atomicAdd(base + 3, w * BSX * BSX);
    }
    if (coef_v != 0.0f) {
        float w = sgn * coef_v;
        atomicAdd(base + 4, w * rx  * ry);
        atomicAdd(base + 5, w * rx  * BSX);
        atomicAdd(base + 6, w * BSX * ry);
        atomicAdd(base + 7, w * BSX * BSX);
    }
}

// ---------------------------------------------------------------- scans
// Exclusive y-scan of fields {1,3,5,7}. One block per x, one thread per y.
__global__ void scan_y(float* __restrict__ W) {
    int x = blockIdx.x;
    int y = threadIdx.x;
    float* base = W + (size_t)(x * NBY + y) * 8;
    __shared__ float4 tmp[NBY];
    tmp[y] = make_float4(base[1], base[3], base[5], base[7]);
    __syncthreads();
    for (int d = 1; d < NBY; d <<= 1) {
        float4 add = make_float4(0.f, 0.f, 0.f, 0.f);
        if (y >= d) add = tmp[y - d];
        __syncthreads();
        tmp[y].x += add.x; tmp[y].y += add.y; tmp[y].z += add.z; tmp[y].w += add.w;
        __syncthreads();
    }
    float4 ex = (y > 0) ? tmp[y - 1] : make_float4(0.f, 0.f, 0.f, 0.f);
    base[1] = ex.x; base[3] = ex.y; base[5] = ex.z; base[7] = ex.w;
}

// Exclusive x-scan of fields {2,3,6,7} fused with util computation.
// One block per y, one thread per x.
__global__ void scan_x_util(float* __restrict__ W, float* __restrict__ util) {
    int y = blockIdx.x;
    int x = threadIdx.x;
    float* base = W + (size_t)(x * NBY + y) * 8;
    __shared__ float4 tmp[NBX];
    tmp[x] = make_float4(base[2], base[3], base[6], base[7]);
    __syncthreads();
    for (int d = 1; d < NBX; d <<= 1) {
        float4 add = make_float4(0.f, 0.f, 0.f, 0.f);
        if (x >= d) add = tmp[x - d];
        __syncthreads();
        tmp[x].x += add.x; tmp[x].y += add.y; tmp[x].z += add.z; tmp[x].w += add.w;
        __syncthreads();
    }
    float4 ex = (x > 0) ? tmp[x - 1] : make_float4(0.f, 0.f, 0.f, 0.f);
    float H = base[0] + base[1] + ex.x + ex.y;
    float V = base[4] + base[5] + ex.z + ex.w;
    float u = fmaxf(H, V) * (1.0f / (BIN_AREA * 1.5f));
    u = fminf(fmaxf(u, 0.5f), 2.0f);
    util[x * NBY + y] = u;
}

// ---------------------------------------------------------------- node phase
__global__ void node_area(const float* __restrict__ pos,
                          const float* __restrict__ nsx,
                          const float* __restrict__ nsy,
                          const float* __restrict__ util,
                          float* __restrict__ out) {
    int m = blockIdx.x * 256 + threadIdx.x;
    if (m >= NUM_MOVABLE) return;
    float xl = pos[m];
    float yl = pos[NUM_NODES + m];
    float xh = xl + nsx[m];
    float yh = yl + nsy[m];
    int bx0 = max(0, min((int)(xl * INV_BS), NBX - 1));
    int bx1 = max(0, min((int)(xh * INV_BS), NBX - 1));
    int by0 = max(0, min((int)(yl * INV_BS), NBY - 1));
    int by1 = max(0, min((int)(yh * INV_BS), NBY - 1));
    float acc = 0.0f;
    for (int bx = bx0; bx <= bx1; ++bx) {
        float ox = fminf(xh, (float)(bx + 1) * BSX) - fmaxf(xl, (float)bx * BSX);
        if (ox <= 0.0f) continue;
        const float* urow = util + bx * NBY;
        float inner = 0.0f;
        for (int by = by0; by <= by1; ++by) {
            float oy = fminf(yh, (float)(by + 1) * BSX) - fmaxf(yl, (float)by * BSX);
            if (oy > 0.0f) inner += oy * urow[by];
        }
        acc += ox * inner;
    }
    out[m] = acc;
}

extern "C" void kernel_launch(void* const* d_in, const int* in_sizes, int n_in,
                              void* d_out, int out_size, void* d_ws, size_t ws_size,
                              hipStream_t stream) {
    const float* pos          = (const float*)d_in[0];
    const float* pin_pos      = (const float*)d_in[1];
    const float* node_size_x  = (const float*)d_in[2];
    const float* node_size_y  = (const float*)d_in[3];
    const int*   netpin_start = (const int*)d_in[4];
    const int*   flat_netpin  = (const int*)d_in[5];

    unsigned* bmin = (unsigned*)d_ws;                       // 2N u32
    unsigned* bmax = bmin + 2 * NUM_NETS;                   // 2N u32
    float*    W    = (float*)(bmax + 2 * NUM_NETS);         // GRID*8 f32
    float*    util = W + (size_t)GRID * 8;                  // GRID f32
    float*    out  = (float*)d_out;

    hipMemsetAsync(bmin, 0xFF, (size_t)2 * NUM_NETS * sizeof(unsigned), stream);
    hipMemsetAsync(bmax, 0x00, (size_t)2 * NUM_NETS * sizeof(unsigned), stream);
    hipMemsetAsync(W,    0x00, (size_t)GRID * 8 * sizeof(float), stream);

    pin_bbox<<<(NUM_PINS + 255) / 256, 256, 0, stream>>>(
        pin_pos, netpin_start, flat_netpin, bmin, bmax);
    net_splat2<<<(4 * NUM_NETS + 255) / 256, 256, 0, stream>>>(bmin, bmax, W);
    scan_y<<<NBX, NBY, 0, stream>>>(W);
    scan_x_util<<<NBY, NBX, 0, stream>>>(W, util);
    node_area<<<(NUM_MOVABLE + 255) / 256, 256, 0, stream>>>(
        pos, node_size_x, node_size_y, util, out);
}

// Round 3
// 220.318 us; speedup vs baseline: 1.1641x; 1.1641x over previous
//
#include <hip/hip_runtime.h>

#define NUM_NODES   120000
#define NUM_MOVABLE 100000
#define NUM_NETS    100000
#define NUM_PINS    400000
#define NBX 256
#define NBY 256
#define GRID (NBX*NBY)

constexpr float BSX      = 1000.0f / 256.0f;   // 3.90625 exact in binary
constexpr float INV_BS   = 256.0f / 1000.0f;
constexpr float BIN_AREA = BSX * BSX;
constexpr float EPSV     = 1e-6f;

// Workspace layout:
//   bmin: u32[2*NUM_NETS]  (xmn, ymn; memset 0xFF)
//   bmax: u32[2*NUM_NETS]  (xmx, ymx; memset 0x00)
//   W:    float[8*GRID]    SoA grids: 0 P_h, 1 Cx_h, 2 Cy_h, 3 Q_h, 4..7 V
//   util: float[GRID]

// ---------------------------------------------------------------- pin phase
// One thread per pin slot. net_id non-decreasing in slot order. Wave-level
// segmented min/max scan; segments fully contained in one wave (~94% of
// nets) have a unique tail lane -> plain store. Only wave-crossing segments
// use atomics (~50k total vs 1.7M before).
__global__ void pin_bbox(const float* __restrict__ pin_pos,
                         const int* __restrict__ netpin_start,
                         const int* __restrict__ flat_netpin,
                         unsigned* __restrict__ bmin,
                         unsigned* __restrict__ bmax) {
    int t = blockIdx.x * 256 + threadIdx.x;
    int key = -4;              // (net<<1)|head_seen ; invalid sentinel
    int net = -1, segend = -1;
    float xmn = 3.4e38f, xmx = -3.4e38f, ymn = 3.4e38f, ymx = -3.4e38f;
    if (t < NUM_PINS) {
        int lo = 0, hi = NUM_NETS + 1;
        while (lo < hi) {
            int mid = (lo + hi) >> 1;
            if (netpin_start[mid] <= t) lo = mid + 1; else hi = mid;
        }
        net = min(lo - 1, NUM_NETS - 1);
        int s = netpin_start[net];
        segend  = netpin_start[net + 1];
        key = (net << 1) | (s == t ? 1 : 0);
        int p = flat_netpin[t];
        float px = pin_pos[p];
        float py = pin_pos[NUM_PINS + p];
        xmn = px; xmx = px; ymn = py; ymx = py;
    }
    int lane = threadIdx.x & 63;
    for (int d = 1; d < 64; d <<= 1) {
        int   ku = __shfl_up(key, d);
        float a  = __shfl_up(xmn, d);
        float b  = __shfl_up(xmx, d);
        float c  = __shfl_up(ymn, d);
        float e  = __shfl_up(ymx, d);
        if (lane >= d && (ku >> 1) == (key >> 1)) {
            xmn = fminf(xmn, a); xmx = fmaxf(xmx, b);
            ymn = fminf(ymn, c); ymx = fmaxf(ymx, e);
            key |= (ku & 1);
        }
    }
    int nextkey = __shfl_down(key, 1);
    if (t >= NUM_PINS || net < 0) return;
    bool netchg = (lane == 63) ? false : ((nextkey >> 1) != (key >> 1));
    bool tail   = (lane == 63) || netchg;
    if (!tail) return;
    bool true_end  = netchg || (segend == t + 1);
    bool contained = (key & 1) != 0;
    unsigned uxmn = __float_as_uint(xmn), uymn = __float_as_uint(ymn);
    unsigned uxmx = __float_as_uint(xmx), uymx = __float_as_uint(ymx);
    if (contained && true_end) {
        // sole writer for this net anywhere in the grid
        bmin[net]            = uxmn;
        bmin[NUM_NETS + net] = uymn;
        bmax[net]            = uxmx;
        bmax[NUM_NETS + net] = uymx;
    } else {
        atomicMin(bmin + net,            uxmn);
        atomicMin(bmin + NUM_NETS + net, uymn);
        atomicMax(bmax + net,            uxmx);
        atomicMax(bmax + NUM_NETS + net, uymx);
    }
}

// ---------------------------------------------------------------- splat phase
// One thread per (net, corner). SoA grids: each of the 8 atomics goes to a
// different 256KB grid -> spread across L2 banks/channels (measured faster
// than the interleaved layout).
__global__ void net_splat3(const unsigned* __restrict__ bmin,
                           const unsigned* __restrict__ bmax,
                           float* __restrict__ W) {
    int t = blockIdx.x * 256 + threadIdx.x;
    if (t >= 4 * NUM_NETS) return;
    int n = t >> 2;
    int c = t & 3;           // 0:(lo,lo,+) 1:(lo,hi,-) 2:(hi,lo,-) 3:(hi,hi,+)

    unsigned emnx = bmin[n];
    if (emnx == 0xFFFFFFFFu) return;   // empty net
    float xmn = __uint_as_float(emnx);
    float ymn = __uint_as_float(bmin[NUM_NETS + n]);
    float xmx = __uint_as_float(bmax[n]);
    float ymx = __uint_as_float(bmax[NUM_NETS + n]);

    float span_x = xmx - xmn, span_y = ymx - ymn;
    float coef_h = (span_y > EPSV) ? 1.0f / span_y : 0.0f;
    float coef_v = (span_x > EPSV) ? 1.0f / span_x : 0.0f;
    if (coef_h == 0.0f && coef_v == 0.0f) return;

    int bxl = min((int)(xmn * INV_BS), NBX - 1);
    int bxh = min((int)(xmx * INV_BS), NBX - 1);
    int byl = min((int)(ymn * INV_BS), NBY - 1);
    int byh = min((int)(ymx * INV_BS), NBY - 1);

    int   bx  = (c & 2) ? bxh : bxl;
    int   by  = (c & 1) ? byh : byl;
    float rx  = (c & 2) ? ((float)(bxh + 1) * BSX - xmx) : ((float)(bxl + 1) * BSX - xmn);
    float ry  = (c & 1) ? ((float)(byh + 1) * BSX - ymx) : ((float)(byl + 1) * BSX - ymn);
    float sgn = ((c == 0) | (c == 3)) ? 1.0f : -1.0f;

    int idx = bx * NBY + by;
    if (coef_h != 0.0f) {
        float w = sgn * coef_h;
        atomicAdd(W + 0 * GRID + idx, w * rx  * ry);
        atomicAdd(W + 1 * GRID + idx, w * rx  * BSX);
        atomicAdd(W + 2 * GRID + idx, w * BSX * ry);
        atomicAdd(W + 3 * GRID + idx, w * BSX * BSX);
    }
    if (coef_v != 0.0f) {
        float w = sgn * coef_v;
        atomicAdd(W + 4 * GRID + idx, w * rx  * ry);
        atomicAdd(W + 5 * GRID + idx, w * rx  * BSX);
        atomicAdd(W + 6 * GRID + idx, w * BSX * ry);
        atomicAdd(W + 7 * GRID + idx, w * BSX * BSX);
    }
}

// ---------------------------------------------------------------- scans
// Exclusive y-scan of grids {1,3,5,7}. One block per x, one thread per y.
__global__ void scan_y(float* __restrict__ W) {
    int x = blockIdx.x;
    int y = threadIdx.x;
    int idx = x * NBY + y;
    __shared__ float4 tmp[NBY];
    tmp[y] = make_float4(W[1 * GRID + idx], W[3 * GRID + idx],
                         W[5 * GRID + idx], W[7 * GRID + idx]);
    __syncthreads();
    for (int d = 1; d < NBY; d <<= 1) {
        float4 add = make_float4(0.f, 0.f, 0.f, 0.f);
        if (y >= d) add = tmp[y - d];
        __syncthreads();
        tmp[y].x += add.x; tmp[y].y += add.y; tmp[y].z += add.z; tmp[y].w += add.w;
        __syncthreads();
    }
    float4 ex = (y > 0) ? tmp[y - 1] : make_float4(0.f, 0.f, 0.f, 0.f);
    W[1 * GRID + idx] = ex.x;
    W[3 * GRID + idx] = ex.y;
    W[5 * GRID + idx] = ex.z;
    W[7 * GRID + idx] = ex.w;
}

// Exclusive x-scan of grids {2,3,6,7} fused with util computation.
// One block per y, one thread per x.
__global__ void scan_x_util(float* __restrict__ W, float* __restrict__ util) {
    int y = blockIdx.x;
    int x = threadIdx.x;
    int idx = x * NBY + y;
    __shared__ float4 tmp[NBX];
    tmp[x] = make_float4(W[2 * GRID + idx], W[3 * GRID + idx],
                         W[6 * GRID + idx], W[7 * GRID + idx]);
    __syncthreads();
    for (int d = 1; d < NBX; d <<= 1) {
        float4 add = make_float4(0.f, 0.f, 0.f, 0.f);
        if (x >= d) add = tmp[x - d];
        __syncthreads();
        tmp[x].x += add.x; tmp[x].y += add.y; tmp[x].z += add.z; tmp[x].w += add.w;
        __syncthreads();
    }
    float4 ex = (x > 0) ? tmp[x - 1] : make_float4(0.f, 0.f, 0.f, 0.f);
    float H = W[0 * GRID + idx] + W[1 * GRID + idx] + ex.x + ex.y;
    float V = W[4 * GRID + idx] + W[5 * GRID + idx] + ex.z + ex.w;
    float u = fmaxf(H, V) * (1.0f / (BIN_AREA * 1.5f));
    u = fminf(fmaxf(u, 0.5f), 2.0f);
    util[idx] = u;
}

// ---------------------------------------------------------------- node phase
__global__ void node_area(const float* __restrict__ pos,
                          const float* __restrict__ nsx,
                          const float* __restrict__ nsy,
                          const float* __restrict__ util,
                          float* __restrict__ out) {
    int m = blockIdx.x * 256 + threadIdx.x;
    if (m >= NUM_MOVABLE) return;
    float xl = pos[m];
    float yl = pos[NUM_NODES + m];
    float xh = xl + nsx[m];
    float yh = yl + nsy[m];
    int bx0 = max(0, min((int)(xl * INV_BS), NBX - 1));
    int bx1 = max(0, min((int)(xh * INV_BS), NBX - 1));
    int by0 = max(0, min((int)(yl * INV_BS), NBY - 1));
    int by1 = max(0, min((int)(yh * INV_BS), NBY - 1));
    float acc = 0.0f;
    for (int bx = bx0; bx <= bx1; ++bx) {
        float ox = fminf(xh, (float)(bx + 1) * BSX) - fmaxf(xl, (float)bx * BSX);
        if (ox <= 0.0f) continue;
        const float* urow = util + bx * NBY;
        float inner = 0.0f;
        for (int by = by0; by <= by1; ++by) {
            float oy = fminf(yh, (float)(by + 1) * BSX) - fmaxf(yl, (float)by * BSX);
            if (oy > 0.0f) inner += oy * urow[by];
        }
        acc += ox * inner;
    }
    out[m] = acc;
}

extern "C" void kernel_launch(void* const* d_in, const int* in_sizes, int n_in,
                              void* d_out, int out_size, void* d_ws, size_t ws_size,
                              hipStream_t stream) {
    const float* pos          = (const float*)d_in[0];
    const float* pin_pos      = (const float*)d_in[1];
    const float* node_size_x  = (const float*)d_in[2];
    const float* node_size_y  = (const float*)d_in[3];
    const int*   netpin_start = (const int*)d_in[4];
    const int*   flat_netpin  = (const int*)d_in[5];

    unsigned* bmin = (unsigned*)d_ws;                       // 2N u32
    unsigned* bmax = bmin + 2 * NUM_NETS;                   // 2N u32
    float*    W    = (float*)(bmax + 2 * NUM_NETS);         // 8*GRID f32
    float*    util = W + (size_t)8 * GRID;                  // GRID f32
    float*    out  = (float*)d_out;

    hipMemsetAsync(bmin, 0xFF, (size_t)2 * NUM_NETS * sizeof(unsigned), stream);
    hipMemsetAsync(bmax, 0x00, (size_t)2 * NUM_NETS * sizeof(unsigned), stream);
    hipMemsetAsync(W,    0x00, (size_t)8 * GRID * sizeof(float), stream);

    pin_bbox<<<(NUM_PINS + 255) / 256, 256, 0, stream>>>(
        pin_pos, netpin_start, flat_netpin, bmin, bmax);
    net_splat3<<<(4 * NUM_NETS + 255) / 256, 256, 0, stream>>>(bmin, bmax, W);
    scan_y<<<NBX, NBY, 0, stream>>>(W);
    scan_x_util<<<NBY, NBX, 0, stream>>>(W, util);
    node_area<<<(NUM_MOVABLE + 255) / 256, 256, 0, stream>>>(
        pos, node_size_x, node_size_y, util, out);
}

// Round 4
// 148.591 us; speedup vs baseline: 1.7261x; 1.4827x over previous
//
#include <hip/hip_runtime.h>

#define NUM_NODES   120000
#define NUM_MOVABLE 100000
#define NUM_NETS    100000
#define NUM_PINS    400000
#define NBX 256
#define NBY 256
#define GRID (NBX*NBY)

constexpr float BSX      = 1000.0f / 256.0f;   // 3.90625 exact in binary
constexpr float INV_BS   = 256.0f / 1000.0f;
constexpr float BIN_AREA = BSX * BSX;
constexpr float EPSV     = 1e-6f;

// Workspace layout:
//   bbox: float4[NUM_NETS]  {xmn, ymn, xmx, ymx}  (init: {+inf,+inf,0,0})
//   A_h, B_h, A_v, B_v: float[GRID] each, [x*NBY+y]
//     H(x,y) = A_h[x][y] + sum_{x'<x} B_h[x'][y]   (same for V)
//   util: float[GRID]

__global__ void init_bbox(float4* __restrict__ bbox) {
    int n = blockIdx.x * 256 + threadIdx.x;
    if (n < NUM_NETS) {
        float inf = __uint_as_float(0x7F800000u);
        bbox[n] = make_float4(inf, inf, 0.0f, 0.0f);
    }
}

// ---------------------------------------------------------------- pin phase
// One thread per pin slot; wave-segmented min/max scan (net_id sorted along
// slots). Nets fully contained in one wave -> single plain float4 store.
// Only wave-crossing nets use atomics.
__global__ void pin_bbox(const float* __restrict__ pin_pos,
                         const int* __restrict__ netpin_start,
                         const int* __restrict__ flat_netpin,
                         float4* __restrict__ bbox) {
    int t = blockIdx.x * 256 + threadIdx.x;
    int key = -4;              // (net<<1)|head_seen ; invalid sentinel
    int net = -1, segend = -1;
    float xmn = 3.4e38f, xmx = -3.4e38f, ymn = 3.4e38f, ymx = -3.4e38f;
    if (t < NUM_PINS) {
        int lo = 0, hi = NUM_NETS + 1;
        while (lo < hi) {
            int mid = (lo + hi) >> 1;
            if (netpin_start[mid] <= t) lo = mid + 1; else hi = mid;
        }
        net = min(lo - 1, NUM_NETS - 1);
        int s = netpin_start[net];
        segend = netpin_start[net + 1];
        key = (net << 1) | (s == t ? 1 : 0);
        int p = flat_netpin[t];
        float px = pin_pos[p];
        float py = pin_pos[NUM_PINS + p];
        xmn = px; xmx = px; ymn = py; ymx = py;
    }
    int lane = threadIdx.x & 63;
    for (int d = 1; d < 64; d <<= 1) {
        int   ku = __shfl_up(key, d);
        float a  = __shfl_up(xmn, d);
        float b  = __shfl_up(xmx, d);
        float c  = __shfl_up(ymn, d);
        float e  = __shfl_up(ymx, d);
        if (lane >= d && (ku >> 1) == (key >> 1)) {
            xmn = fminf(xmn, a); xmx = fmaxf(xmx, b);
            ymn = fminf(ymn, c); ymx = fmaxf(ymx, e);
            key |= (ku & 1);
        }
    }
    int nextkey = __shfl_down(key, 1);
    if (t >= NUM_PINS || net < 0) return;
    bool netchg = (lane == 63) ? false : ((nextkey >> 1) != (key >> 1));
    bool tail   = (lane == 63) || netchg;
    if (!tail) return;
    bool true_end  = netchg || (segend == t + 1);
    bool contained = (key & 1) != 0;
    if (contained && true_end) {
        bbox[net] = make_float4(xmn, ymn, xmx, ymx);   // sole writer
    } else {
        unsigned* b = (unsigned*)(bbox + net);
        atomicMin(b + 0, __float_as_uint(xmn));   // coords >= 0: uint order ok
        atomicMin(b + 1, __float_as_uint(ymn));
        atomicMax(b + 2, __float_as_uint(xmx));
        atomicMax(b + 3, __float_as_uint(ymx));
    }
}

// ---------------------------------------------------------------- splat phase
// One block per bx row. Scans all net bboxes (L2-resident), accumulates
// matching corner-columns into LDS, y-scans in-block, emits A/B row arrays.
// No global atomics at all.
__global__ __launch_bounds__(1024) void splat_rows(
        const float4* __restrict__ bbox,
        float* __restrict__ A_h, float* __restrict__ B_h,
        float* __restrict__ A_v, float* __restrict__ B_v) {
    int bx = blockIdx.x;
    int t  = threadIdx.x;
    __shared__ float F[8][NBY];  // 0 P_h, 1 CX_h, 2 CY_h, 3 Q_h, 4..7 same V
    for (int i = t; i < 8 * NBY; i += 1024) ((float*)F)[i] = 0.0f;
    __syncthreads();

    for (int n = t; n < NUM_NETS; n += 1024) {
        float4 b = bbox[n];
        float span_x = b.z - b.x, span_y = b.w - b.y;   // empty net -> -inf
        float coef_h = (span_y > EPSV) ? 1.0f / span_y : 0.0f;
        float coef_v = (span_x > EPSV) ? 1.0f / span_x : 0.0f;
        if (coef_h == 0.0f && coef_v == 0.0f) continue;
        int bxl = min((int)(b.x * INV_BS), NBX - 1);
        int bxh = min((int)(b.z * INV_BS), NBX - 1);
        if (bxl != bx && bxh != bx) continue;
        int byl = min((int)(b.y * INV_BS), NBY - 1);
        int byh = min((int)(b.w * INV_BS), NBY - 1);
        float ryl = (float)(byl + 1) * BSX - b.y;
        float ryh = (float)(byh + 1) * BSX - b.w;
        #pragma unroll
        for (int side = 0; side < 2; ++side) {
            bool active = (side == 0) ? (bxl == bx) : (bxh == bx);
            if (!active) continue;
            float rx = (side == 0) ? ((float)(bxl + 1) * BSX - b.x)
                                   : ((float)(bxh + 1) * BSX - b.z);
            float s0 = (side == 0) ? 1.0f : -1.0f;   // sign at byl; -s0 at byh
            if (coef_h != 0.0f) {
                float w0 = s0 * coef_h, w1 = -s0 * coef_h;
                atomicAdd(&F[0][byl], w0 * rx  * ryl);
                atomicAdd(&F[1][byl], w0 * rx  * BSX);
                atomicAdd(&F[2][byl], w0 * BSX * ryl);
                atomicAdd(&F[3][byl], w0 * BSX * BSX);
                atomicAdd(&F[0][byh], w1 * rx  * ryh);
                atomicAdd(&F[1][byh], w1 * rx  * BSX);
                atomicAdd(&F[2][byh], w1 * BSX * ryh);
                atomicAdd(&F[3][byh], w1 * BSX * BSX);
            }
            if (coef_v != 0.0f) {
                float w0 = s0 * coef_v, w1 = -s0 * coef_v;
                atomicAdd(&F[4][byl], w0 * rx  * ryl);
                atomicAdd(&F[5][byl], w0 * rx  * BSX);
                atomicAdd(&F[6][byl], w0 * BSX * ryl);
                atomicAdd(&F[7][byl], w0 * BSX * BSX);
                atomicAdd(&F[4][byh], w1 * rx  * ryh);
                atomicAdd(&F[5][byh], w1 * rx  * BSX);
                atomicAdd(&F[6][byh], w1 * BSX * ryh);
                atomicAdd(&F[7][byh], w1 * BSX * BSX);
            }
        }
    }
    __syncthreads();

    // In-block inclusive y-scan of fields 1,3,5,7 (CX_h, Q_h, CX_v, Q_v).
    // 4 groups of 256 threads scan in parallel.
    int g = t >> 8, y = t & 255;
    float* f = F[2 * g + 1];
    for (int d = 1; d < 256; d <<= 1) {
        float add = (y >= d) ? f[y - d] : 0.0f;
        __syncthreads();
        f[y] += add;
        __syncthreads();
    }
    // Emit: group g writes one of the 4 output arrays.
    // A = P + exclusive(CX); B = CY + exclusive(Q)
    float ex = (y > 0) ? F[2 * g + 1][y - 1] : 0.0f;
    float val = F[2 * g][y] + ex;
    float* outs[4] = {A_h, B_h, A_v, B_v};
    outs[g][bx * NBY + y] = val;
}

// ---------------------------------------------------------------- x-scan+util
// One block per y, thread per x. Exclusive x-scan of B fields, fused util.
__global__ void scan_x_util(const float* __restrict__ A_h, const float* __restrict__ B_h,
                            const float* __restrict__ A_v, const float* __restrict__ B_v,
                            float* __restrict__ util) {
    int y = blockIdx.x, x = threadIdx.x;
    int idx = x * NBY + y;
    __shared__ float2 tmp[NBX];
    tmp[x] = make_float2(B_h[idx], B_v[idx]);
    __syncthreads();
    for (int d = 1; d < 256; d <<= 1) {
        float2 add = (x >= d) ? tmp[x - d] : make_float2(0.f, 0.f);
        __syncthreads();
        tmp[x].x += add.x; tmp[x].y += add.y;
        __syncthreads();
    }
    float2 ex = (x > 0) ? tmp[x - 1] : make_float2(0.f, 0.f);
    float H = A_h[idx] + ex.x;
    float V = A_v[idx] + ex.y;
    float u = fmaxf(H, V) * (1.0f / (BIN_AREA * 1.5f));
    util[idx] = fminf(fmaxf(u, 0.5f), 2.0f);
}

// ---------------------------------------------------------------- node phase
__global__ void node_area(const float* __restrict__ pos,
                          const float* __restrict__ nsx,
                          const float* __restrict__ nsy,
                          const float* __restrict__ util,
                          float* __restrict__ out) {
    int m = blockIdx.x * 256 + threadIdx.x;
    if (m >= NUM_MOVABLE) return;
    float xl = pos[m];
    float yl = pos[NUM_NODES + m];
    float xh = xl + nsx[m];
    float yh = yl + nsy[m];
    int bx0 = max(0, min((int)(xl * INV_BS), NBX - 1));
    int bx1 = max(0, min((int)(xh * INV_BS), NBX - 1));
    int by0 = max(0, min((int)(yl * INV_BS), NBY - 1));
    int by1 = max(0, min((int)(yh * INV_BS), NBY - 1));
    float acc = 0.0f;
    for (int bx = bx0; bx <= bx1; ++bx) {
        float ox = fminf(xh, (float)(bx + 1) * BSX) - fmaxf(xl, (float)bx * BSX);
        if (ox <= 0.0f) continue;
        const float* urow = util + bx * NBY;
        float inner = 0.0f;
        for (int by = by0; by <= by1; ++by) {
            float oy = fminf(yh, (float)(by + 1) * BSX) - fmaxf(yl, (float)by * BSX);
            if (oy > 0.0f) inner += oy * urow[by];
        }
        acc += ox * inner;
    }
    out[m] = acc;
}

extern "C" void kernel_launch(void* const* d_in, const int* in_sizes, int n_in,
                              void* d_out, int out_size, void* d_ws, size_t ws_size,
                              hipStream_t stream) {
    const float* pos          = (const float*)d_in[0];
    const float* pin_pos      = (const float*)d_in[1];
    const float* node_size_x  = (const float*)d_in[2];
    const float* node_size_y  = (const float*)d_in[3];
    const int*   netpin_start = (const int*)d_in[4];
    const int*   flat_netpin  = (const int*)d_in[5];

    float4* bbox = (float4*)d_ws;                     // NUM_NETS float4
    float*  A_h  = (float*)(bbox + NUM_NETS);         // GRID
    float*  B_h  = A_h + GRID;
    float*  A_v  = B_h + GRID;
    float*  B_v  = A_v + GRID;
    float*  util = B_v + GRID;
    float*  out  = (float*)d_out;

    init_bbox<<<(NUM_NETS + 255) / 256, 256, 0, stream>>>(bbox);
    pin_bbox<<<(NUM_PINS + 255) / 256, 256, 0, stream>>>(
        pin_pos, netpin_start, flat_netpin, bbox);
    splat_rows<<<NBX, 1024, 0, stream>>>(bbox, A_h, B_h, A_v, B_v);
    scan_x_util<<<NBY, NBX, 0, stream>>>(A_h, B_h, A_v, B_v, util);
    node_area<<<(NUM_MOVABLE + 255) / 256, 256, 0, stream>>>(
        pos, node_size_x, node_size_y, util, out);
}